// Round 8
// baseline (142.986 us; speedup 1.0000x reference)
//
#include <hip/hip_runtime.h>

#define N_TOK 32768
#define H 128
#define I_DIM 512
#define E 8
#define EPS 1e-5f
#define GATE_TPB 128   // tokens per block in k_gate
#define NSLOT_MAX (N_TOK * 2 + E * 32)   // padded slot capacity (65792)

typedef __attribute__((ext_vector_type(8))) short short8;
typedef __attribute__((ext_vector_type(4))) float f32x4;
typedef __attribute__((ext_vector_type(2))) unsigned int u32x2;
typedef __attribute__((ext_vector_type(8))) __bf16 bf16x8;

__device__ inline unsigned short f2bf(float f){
  unsigned int u = __builtin_bit_cast(unsigned int, f);
  u += 0x7fffu + ((u >> 16) & 1u);
  return (unsigned short)(u >> 16);
}
__device__ inline float bf2f(unsigned short s){
  unsigned int u = ((unsigned int)s) << 16;
  return __builtin_bit_cast(float, u);
}
__device__ inline unsigned int pack2(float a, float b){
  return (unsigned int)f2bf(a) | ((unsigned int)f2bf(b) << 16);
}
// fast GELU (tanh form), |err| <= ~3e-4 vs exact erf-GELU
__device__ inline float gelu_fast(float x){
  const float A = 0.10294517f;     // 2*log2(e)*0.7978845608*0.044715
  const float B = 2.30214175f;     // 2*log2(e)*0.7978845608
  float x2 = x * x;
  float v  = __builtin_fmaf(x2, A, B);
  float z  = __builtin_amdgcn_exp2f(v * x);
  float r  = __builtin_amdgcn_rcpf(z + 1.f);
  return __builtin_fmaf(-x, r, x);
}
__device__ inline f32x4 mfma16(short8 a, short8 b, f32x4 c){
  return __builtin_amdgcn_mfma_f32_16x16x32_bf16(
      __builtin_bit_cast(bf16x8, a), __builtin_bit_cast(bf16x8, b), c, 0, 0, 0);
}

// Dense slot-space -> (expert, base, ne). slot0 is the wave's first padded
// slot. Returns -1 if slot0 is beyond all experts or the tile is all-pad.
__device__ inline int slot_to_expert(const int* __restrict__ cnt, int slot0,
                                     int& base, int& ne){
  int e = -1, p = 0;
  #pragma unroll
  for (int q = 0; q < E; ++q){
    int c = cnt[q];
    int pc = (c + 31) & ~31;
    if (slot0 >= p && slot0 < p + pc){ e = q; base = slot0 - p; ne = c; }
    p += pc;
  }
  return e;
}

// ---------------- Kernel A: repack weights to bf16 MFMA fragment order ------
// Frag: lane l holds row (l&15), k=(l>>4)*8+j.
// w1p: [e][it(32)][kt(4)][lane][j] from w1[e][it*16+(l&15)][kt*32+(l>>4)*8+j]
// w2p: [e][ht(8)][kt(16)][lane][j] from w2[e][ht*16+(l&15)][kt*32+(l>>4)*8+j]
__global__ __launch_bounds__(256) void k_prep(const float* __restrict__ w1,
                                              const float* __restrict__ w2,
                                              unsigned short* __restrict__ w1p,
                                              unsigned short* __restrict__ w2p){
  int q = blockIdx.x * 256 + threadIdx.x;   // 0 .. 65535
  int e = q >> 13, rem = q & 8191;
  {
    int it = rem >> 8, kt = (rem >> 6) & 3, l = rem & 63;
    int row = it * 16 + (l & 15), h0 = kt * 32 + (l >> 4) * 8;
    const float* src = w1 + ((size_t)(e * 512 + row) * 128 + h0);
    float4 v0 = *(const float4*)src, v1 = *(const float4*)(src + 4);
    short8 o;
    #pragma unroll
    for (int j = 0; j < 4; ++j){ o[j] = (short)f2bf(v0[j]); o[j+4] = (short)f2bf(v1[j]); }
    *(short8*)(w1p + (size_t)q * 8) = o;
  }
  {
    int ht = rem >> 10, kt = (rem >> 6) & 15, l = rem & 63;
    int row = ht * 16 + (l & 15), i0 = kt * 32 + (l >> 4) * 8;
    const float* src = w2 + ((size_t)(e * 128 + row) * 512 + i0);
    float4 v0 = *(const float4*)src, v1 = *(const float4*)(src + 4);
    short8 o;
    #pragma unroll
    for (int j = 0; j < 4; ++j){ o[j] = (short)f2bf(v0[j]); o[j+4] = (short)f2bf(v1[j]); }
    *(short8*)(w2p + (size_t)q * 8) = o;
  }
}

// ---------------- Kernel B: gating softmax/top2 + token layernorm -----------
__global__ __launch_bounds__(256) void k_gate(const float* __restrict__ x,
                                              const float* __restrict__ gw,
                                              const float* __restrict__ gb,
                                              unsigned short* __restrict__ xn,
                                              int* __restrict__ cnt,
                                              int* __restrict__ list,
                                              float* __restrict__ score){
  __shared__ __align__(16) float gws[E * H];
  __shared__ float gbs[E];
  __shared__ int   lcnt[E];
  __shared__ int   gbase[E];
  __shared__ int   te[2][GATE_TPB];
  __shared__ float tsc[2][GATE_TPB];
  __shared__ int   tlp[2][GATE_TPB];

  int tid = threadIdx.x;
  for (int i = tid; i < E * H; i += 256) gws[i] = gw[i];
  if (tid < E){ gbs[tid] = gb[tid]; lcnt[tid] = 0; }
  __syncthreads();

  int wave = tid >> 6, lane = tid & 63;
  int g = lane >> 3, c8 = lane & 7;
  int tok0 = blockIdx.x * GATE_TPB;
  const float4* gws4 = (const float4*)gws;

  for (int t = 0; t < 4; ++t){
    int lt = t * 32 + wave * 8 + g;
    int tok = tok0 + lt;
    const float4* xr = (const float4*)(x + (size_t)tok * H) + c8 * 4;
    float4 v[4];
    #pragma unroll
    for (int q = 0; q < 4; ++q) v[q] = xr[q];

    float S = 0.f, Q = 0.f;
    float lg[E];
    #pragma unroll
    for (int e = 0; e < E; e++) lg[e] = 0.f;
    #pragma unroll
    for (int q = 0; q < 4; ++q){
      #pragma unroll
      for (int r = 0; r < 4; ++r){
        float f = v[q][r];
        S += f; Q = __builtin_fmaf(f, f, Q);
      }
      #pragma unroll
      for (int e = 0; e < E; e++){
        float4 wv = gws4[e * 32 + c8 * 4 + q];
        #pragma unroll
        for (int r = 0; r < 4; ++r) lg[e] = __builtin_fmaf(v[q][r], wv[r], lg[e]);
      }
    }
    #pragma unroll
    for (int m = 1; m < 8; m <<= 1){
      S += __shfl_xor(S, m);
      Q += __shfl_xor(Q, m);
      #pragma unroll
      for (int e = 0; e < E; e++) lg[e] += __shfl_xor(lg[e], m);
    }

    float mu = S * (1.f / H);
    float var = Q * (1.f / H) - mu * mu;
    float rsig = rsqrtf(fmaxf(var, 0.f) + EPS);

    short8 s0, s1;
    #pragma unroll
    for (int r = 0; r < 4; ++r){
      s0[r]     = (short)f2bf((v[0][r] - mu) * rsig);
      s0[r + 4] = (short)f2bf((v[1][r] - mu) * rsig);
      s1[r]     = (short)f2bf((v[2][r] - mu) * rsig);
      s1[r + 4] = (short)f2bf((v[3][r] - mu) * rsig);
    }
    unsigned short* xo = xn + (size_t)tok * H + c8 * 16;
    *(short8*)xo = s0;
    *(short8*)(xo + 8) = s1;

    if (c8 == 0){
      float mx = -1e30f;
      #pragma unroll
      for (int e = 0; e < E; e++){ lg[e] += gbs[e]; mx = fmaxf(mx, lg[e]); }
      float p[E], sum = 0.f;
      #pragma unroll
      for (int e = 0; e < E; e++){ p[e] = __expf(lg[e] - mx); sum += p[e]; }
      float inv = 1.f / sum;
      int e0 = 0; float p0 = p[0];
      #pragma unroll
      for (int e = 1; e < E; e++) if (p[e] > p0){ e0 = e; p0 = p[e]; }
      int e1 = -1; float p1 = -1.f;
      #pragma unroll
      for (int e = 0; e < E; e++) if (e != e0 && p[e] > p1){ e1 = e; p1 = p[e]; }
      te[0][lt] = e0; tsc[0][lt] = p0 * inv; tlp[0][lt] = atomicAdd(&lcnt[e0], 1);
      te[1][lt] = e1; tsc[1][lt] = p1 * inv; tlp[1][lt] = atomicAdd(&lcnt[e1], 1);
    }
  }
  __syncthreads();
  if (tid < E) gbase[tid] = atomicAdd(&cnt[tid], lcnt[tid]);
  __syncthreads();
  if (tid < GATE_TPB){
    int tok = tok0 + tid;
    #pragma unroll
    for (int k2 = 0; k2 < 2; k2++){
      int ee = te[k2][tid];
      int pos = gbase[ee] + tlp[k2][tid];
      list[ee * N_TOK + pos] = tok;
      score[ee * N_TOK + pos] = tsc[k2][tid];
    }
  }
}

// ---------------- Kernel C1: GEMM1^T + stats, t streamed to global ----------
// DENSE grid over padded slot space (every block works; round-7's per-expert
// worst-case grid left 75% of blocks early-exiting -> 24% occupancy).
// 1 wave = 16 slot-tokens. t stored per 16-slot tile in GEMM2 A-frag layout:
// [tile][kt(16)][lh(4)][il(16)][j(8)] u16, element (token=il, i=kt*32+lh*8+j).
__global__ __launch_bounds__(256, 4) void k_mlp1(
    const unsigned short* __restrict__ xn,
    const float* __restrict__ ln1g, const float* __restrict__ ln1b,
    const unsigned short* __restrict__ w1p,
    const int* __restrict__ cnt, const int* __restrict__ list,
    unsigned short* __restrict__ t, float2* __restrict__ stats){
  int wave = threadIdx.x >> 6, lane = threadIdx.x & 63;
  int slot0 = (blockIdx.x * 4 + wave) * 16;
  int base, ne;
  int e = slot_to_expert(cnt, slot0, base, ne);
  if (e < 0 || base >= ne) return;
  const int l15 = lane & 15, l4 = lane >> 4;

  int tok_ = base + l15 < ne ? list[e * N_TOK + base + l15] : 0;

  // GEMM1 B-frags: a1 = gelu(xn*g1+b1); token=l15, h = kt*32 + l4*8 + j
  short8 b1f[4];
  const float* g1e = ln1g + e * H;
  const float* b1e = ln1b + e * H;
  #pragma unroll
  for (int kt = 0; kt < 4; ++kt){
    int h0 = kt * 32 + l4 * 8;
    float4 ga = *(const float4*)(g1e + h0), gbv = *(const float4*)(g1e + h0 + 4);
    float4 ba = *(const float4*)(b1e + h0), bbv = *(const float4*)(b1e + h0 + 4);
    short8 xv = *(const short8*)(xn + (size_t)tok_ * H + h0);
    short8 o;
    #pragma unroll
    for (int j = 0; j < 8; ++j){
      float f = bf2f((unsigned short)xv[j]);
      float gg = j < 4 ? ga[j] : gbv[j - 4];
      float bb_ = j < 4 ? ba[j] : bbv[j - 4];
      o[j] = (short)f2bf(gelu_fast(__builtin_fmaf(f, gg, bb_)));
    }
    b1f[kt] = o;
  }

  const unsigned short* w1e = w1p + ((size_t)e << 16);
  unsigned short* tb0 = t + ((size_t)(slot0 >> 4) << 13);
  float S0 = 0.f, Q0 = 0.f;

  for (int ch = 0; ch < 4; ++ch){
    f32x4 a0[8];
    #pragma unroll
    for (int ii = 0; ii < 8; ++ii){ f32x4 z = {0.f,0.f,0.f,0.f}; a0[ii] = z; }
    #pragma unroll
    for (int kt = 0; kt < 4; ++kt){
      #pragma unroll
      for (int ii = 0; ii < 8; ++ii){
        int it = ch * 8 + ii;
        short8 af = *(const short8*)(w1e + (size_t)(((it << 2) | kt) << 9) + lane * 8);
        a0[ii] = mfma16(af, b1f[kt], a0[ii]);
      }
    }
    #pragma unroll
    for (int ii = 0; ii < 8; ++ii){
      int it = ch * 8 + ii;
      int kt2 = it >> 1;
      int lh = (it * 2 + (l4 >> 1)) & 3;
      int off = ((kt2 * 4 + lh) * 16 + l15) * 8 + (l4 & 1) * 4;  // u16 units
      u32x2 w0;
      #pragma unroll
      for (int r = 0; r < 4; ++r){
        float v0 = a0[ii][r];
        S0 += v0; Q0 = __builtin_fmaf(v0, v0, Q0);
      }
      w0[0] = pack2(a0[ii][0], a0[ii][1]); w0[1] = pack2(a0[ii][2], a0[ii][3]);
      *(u32x2*)(tb0 + off) = w0;
    }
  }

  S0 += __shfl_xor(S0, 16); Q0 += __shfl_xor(Q0, 16);
  S0 += __shfl_xor(S0, 32); Q0 += __shfl_xor(Q0, 32);
  if (l4 == 0){
    float mu0 = S0 * (1.f / I_DIM);
    float var0 = __builtin_fmaf(Q0, 1.f / I_DIM, -mu0 * mu0);
    float rs0 = rsqrtf(fmaxf(var0, 0.f) + EPS);
    stats[slot0 + l15] = make_float2(rs0, mu0 * rs0);
  }
}

// ---------------- Kernel C2: LN2 + gelu + GEMM2 + epilogue ------------------
// DENSE grid (see C1). 1 wave = 16 slots. t read as coalesced 16B A-frags
// (lane: token=l15, i=kt*32+l4*8+j). mfma(t_frag, w2_frag): C has token=row
// (l4*4+r), h=col(l15) -> epilogue atomics 64B-coalesced per token row.
__global__ __launch_bounds__(256, 4) void k_mlp2(
    const unsigned short* __restrict__ t, const float2* __restrict__ stats,
    const float* __restrict__ ln2g, const float* __restrict__ ln2b,
    const unsigned short* __restrict__ w2p, const float* __restrict__ b2,
    const int* __restrict__ cnt, const int* __restrict__ list,
    const float* __restrict__ score, float* __restrict__ out){
  int wave = threadIdx.x >> 6, lane = threadIdx.x & 63;
  int slot0 = (blockIdx.x * 4 + wave) * 16;
  int base, ne;
  int e = slot_to_expert(cnt, slot0, base, ne);
  if (e < 0 || base >= ne) return;
  const int l15 = lane & 15, l4 = lane >> 4;

  float2 st0 = stats[slot0 + l15];

  const unsigned short* tb0 = t + ((size_t)(slot0 >> 4) << 13);
  const unsigned short* w2e = w2p + ((size_t)e << 16);
  const float* g2e = ln2g + e * I_DIM;
  const float* b2e = ln2b + e * I_DIM;

  f32x4 c0[8];
  #pragma unroll
  for (int ht = 0; ht < 8; ++ht){ f32x4 z = {0.f,0.f,0.f,0.f}; c0[ht] = z; }

  #pragma unroll
  for (int kt = 0; kt < 16; ++kt){
    int i0 = kt * 32 + l4 * 8;
    float4 g2a = *(const float4*)(g2e + i0), g2b = *(const float4*)(g2e + i0 + 4);
    float4 b2a = *(const float4*)(b2e + i0), b2b = *(const float4*)(b2e + i0 + 4);
    short8 tv0 = *(const short8*)(tb0 + (size_t)((kt * 64 + lane) * 8));
    short8 f0;
    #pragma unroll
    for (int j = 0; j < 8; ++j){
      float gg = j < 4 ? g2a[j] : g2b[j - 4];
      float bb_ = j < 4 ? b2a[j] : b2b[j - 4];
      float v0 = __builtin_fmaf(bf2f((unsigned short)tv0[j]), st0.x, -st0.y);
      f0[j] = (short)f2bf(gelu_fast(__builtin_fmaf(v0, gg, bb_)));
    }
    #pragma unroll
    for (int ht = 0; ht < 8; ++ht){
      short8 af = *(const short8*)(w2e + (size_t)(((ht << 4) | kt) << 9) + lane * 8);
      c0[ht] = mfma16(f0, af, c0[ht]);
    }
  }

  // epilogue: token = base + l4*4 + r (row), h = ht*16 + l15 (col)
  int tokR[4]; float scR[4];
  #pragma unroll
  for (int r = 0; r < 4; ++r){
    int s = base + l4 * 4 + r;
    if (s < ne){ tokR[r] = list[e * N_TOK + s]; scR[r] = score[e * N_TOK + s]; }
    else       { tokR[r] = -1;                  scR[r] = 0.f; }
  }
  const float* b2r = b2 + e * H;
  float bb[8];
  #pragma unroll
  for (int ht = 0; ht < 8; ++ht) bb[ht] = b2r[ht * 16 + l15];

  #pragma unroll
  for (int r = 0; r < 4; ++r){
    if (tokR[r] >= 0){
      float* orow = out + (size_t)tokR[r] * H + l15;
      float sc = scR[r];
      #pragma unroll
      for (int ht = 0; ht < 8; ++ht)
        atomicAdd(orow + ht * 16, (c0[ht][r] + bb[ht]) * sc);
    }
  }
}

extern "C" void kernel_launch(void* const* d_in, const int* in_sizes, int n_in,
                              void* d_out, int out_size, void* d_ws, size_t ws_size,
                              hipStream_t stream){
  const float* x     = (const float*)d_in[0];
  const float* gw    = (const float*)d_in[1];
  const float* gb    = (const float*)d_in[2];
  const float* ln1g  = (const float*)d_in[3];
  const float* ln1b  = (const float*)d_in[4];
  const float* w1    = (const float*)d_in[5];
  const float* ln2g  = (const float*)d_in[6];
  const float* ln2b  = (const float*)d_in[7];
  const float* w2    = (const float*)d_in[8];
  const float* b2    = (const float*)d_in[9];
  float* out = (float*)d_out;

  char* w = (char*)d_ws;
  unsigned short* xn  = (unsigned short*)w;  w += (size_t)N_TOK * H * 2;      // 8.39 MB
  unsigned short* w1p = (unsigned short*)w;  w += (size_t)E * I_DIM * H * 2;  // 1.05 MB
  unsigned short* w2p = (unsigned short*)w;  w += (size_t)E * H * I_DIM * 2;  // 1.05 MB
  int*    list  = (int*)w;                   w += (size_t)E * N_TOK * 4;      // 1.05 MB
  float*  score = (float*)w;                 w += (size_t)E * N_TOK * 4;      // 1.05 MB
  int*    cnt   = (int*)w;                   w += 256;
  float2* stats = (float2*)w;                w += (size_t)NSLOT_MAX * 8;      // 0.53 MB
  unsigned short* t = (unsigned short*)w;    w += (size_t)NSLOT_MAX * I_DIM * 2; // 67.4 MB

  hipMemsetAsync(cnt, 0, 256, stream);
  hipMemsetAsync(out, 0, (size_t)out_size * sizeof(float), stream);

  k_prep<<<dim3(256), dim3(256), 0, stream>>>(w1, w2, w1p, w2p);
  k_gate<<<dim3(N_TOK / GATE_TPB), dim3(256), 0, stream>>>(x, gw, gb, xn, cnt, list, score);
  k_mlp1<<<dim3(NSLOT_MAX / 64), dim3(256), 0, stream>>>(
      xn, ln1g, ln1b, w1p, cnt, list, t, stats);
  k_mlp2<<<dim3(NSLOT_MAX / 64), dim3(256), 0, stream>>>(
      t, stats, ln2g, ln2b, w2p, b2, cnt, list, score, out);
}

// Round 9
// 99.435 us; speedup vs baseline: 1.4380x; 1.4380x over previous
//
#include <hip/hip_runtime.h>

#define N_TOK 32768
#define H 128
#define I_DIM 512
#define E 8
#define EPS 1e-5f
#define GATE_TPB 128   // tokens per block in k_gate
#define NSLOT_MAX (N_TOK * 2 + E * 32)   // padded slot capacity (65792)

typedef __attribute__((ext_vector_type(8))) short short8;
typedef __attribute__((ext_vector_type(4))) float f32x4;
typedef __attribute__((ext_vector_type(2))) unsigned int u32x2;
typedef __attribute__((ext_vector_type(8))) __bf16 bf16x8;

__device__ inline unsigned short f2bf(float f){
  unsigned int u = __builtin_bit_cast(unsigned int, f);
  u += 0x7fffu + ((u >> 16) & 1u);
  return (unsigned short)(u >> 16);
}
__device__ inline float bf2f(unsigned short s){
  unsigned int u = ((unsigned int)s) << 16;
  return __builtin_bit_cast(float, u);
}
__device__ inline unsigned int pack2(float a, float b){
  return (unsigned int)f2bf(a) | ((unsigned int)f2bf(b) << 16);
}
// fast GELU (tanh form), |err| <= ~3e-4 vs exact erf-GELU
__device__ inline float gelu_fast(float x){
  const float A = 0.10294517f;     // 2*log2(e)*0.7978845608*0.044715
  const float B = 2.30214175f;     // 2*log2(e)*0.7978845608
  float x2 = x * x;
  float v  = __builtin_fmaf(x2, A, B);
  float z  = __builtin_amdgcn_exp2f(v * x);
  float r  = __builtin_amdgcn_rcpf(z + 1.f);
  return __builtin_fmaf(-x, r, x);
}
__device__ inline f32x4 mfma16(short8 a, short8 b, f32x4 c){
  return __builtin_amdgcn_mfma_f32_16x16x32_bf16(
      __builtin_bit_cast(bf16x8, a), __builtin_bit_cast(bf16x8, b), c, 0, 0, 0);
}

// Dense slot-space -> (expert, base, ne).
__device__ inline int slot_to_expert(const int* __restrict__ cnt, int slot0,
                                     int& base, int& ne){
  int e = -1, p = 0;
  #pragma unroll
  for (int q = 0; q < E; ++q){
    int c = cnt[q];
    int pc = (c + 31) & ~31;
    if (slot0 >= p && slot0 < p + pc){ e = q; base = slot0 - p; ne = c; }
    p += pc;
  }
  return e;
}

// ---------------- Kernel A: repack weights to bf16 MFMA fragment order ------
// Frag: lane l holds row (l&15), k=(l>>4)*8+j.
// w1p: [e][it(32)][kt(4)][lane][j] from w1[e][it*16+(l&15)][kt*32+(l>>4)*8+j]
// w2p: [e][ht(8)][kt(16)][lane][j] from w2[e][ht*16+(l&15)][kt*32+(l>>4)*8+j]
__global__ __launch_bounds__(256) void k_prep(const float* __restrict__ w1,
                                              const float* __restrict__ w2,
                                              unsigned short* __restrict__ w1p,
                                              unsigned short* __restrict__ w2p){
  int q = blockIdx.x * 256 + threadIdx.x;   // 0 .. 65535
  int e = q >> 13, rem = q & 8191;
  {
    int it = rem >> 8, kt = (rem >> 6) & 3, l = rem & 63;
    int row = it * 16 + (l & 15), h0 = kt * 32 + (l >> 4) * 8;
    const float* src = w1 + ((size_t)(e * 512 + row) * 128 + h0);
    float4 v0 = *(const float4*)src, v1 = *(const float4*)(src + 4);
    short8 o;
    #pragma unroll
    for (int j = 0; j < 4; ++j){ o[j] = (short)f2bf(v0[j]); o[j+4] = (short)f2bf(v1[j]); }
    *(short8*)(w1p + (size_t)q * 8) = o;
  }
  {
    int ht = rem >> 10, kt = (rem >> 6) & 15, l = rem & 63;
    int row = ht * 16 + (l & 15), i0 = kt * 32 + (l >> 4) * 8;
    const float* src = w2 + ((size_t)(e * 128 + row) * 512 + i0);
    float4 v0 = *(const float4*)src, v1 = *(const float4*)(src + 4);
    short8 o;
    #pragma unroll
    for (int j = 0; j < 4; ++j){ o[j] = (short)f2bf(v0[j]); o[j+4] = (short)f2bf(v1[j]); }
    *(short8*)(w2p + (size_t)q * 8) = o;
  }
}

// ---------------- Kernel B: gating softmax/top2 + token layernorm -----------
__global__ __launch_bounds__(256) void k_gate(const float* __restrict__ x,
                                              const float* __restrict__ gw,
                                              const float* __restrict__ gb,
                                              unsigned short* __restrict__ xn,
                                              int* __restrict__ cnt,
                                              int* __restrict__ list,
                                              float* __restrict__ score){
  __shared__ __align__(16) float gws[E * H];
  __shared__ float gbs[E];
  __shared__ int   lcnt[E];
  __shared__ int   gbase[E];
  __shared__ int   te[2][GATE_TPB];
  __shared__ float tsc[2][GATE_TPB];
  __shared__ int   tlp[2][GATE_TPB];

  int tid = threadIdx.x;
  for (int i = tid; i < E * H; i += 256) gws[i] = gw[i];
  if (tid < E){ gbs[tid] = gb[tid]; lcnt[tid] = 0; }
  __syncthreads();

  int wave = tid >> 6, lane = tid & 63;
  int g = lane >> 3, c8 = lane & 7;
  int tok0 = blockIdx.x * GATE_TPB;
  const float4* gws4 = (const float4*)gws;

  for (int t = 0; t < 4; ++t){
    int lt = t * 32 + wave * 8 + g;
    int tok = tok0 + lt;
    const float4* xr = (const float4*)(x + (size_t)tok * H) + c8 * 4;
    float4 v[4];
    #pragma unroll
    for (int q = 0; q < 4; ++q) v[q] = xr[q];

    float S = 0.f, Q = 0.f;
    float lg[E];
    #pragma unroll
    for (int e = 0; e < E; e++) lg[e] = 0.f;
    #pragma unroll
    for (int q = 0; q < 4; ++q){
      #pragma unroll
      for (int r = 0; r < 4; ++r){
        float f = v[q][r];
        S += f; Q = __builtin_fmaf(f, f, Q);
      }
      #pragma unroll
      for (int e = 0; e < E; e++){
        float4 wv = gws4[e * 32 + c8 * 4 + q];
        #pragma unroll
        for (int r = 0; r < 4; ++r) lg[e] = __builtin_fmaf(v[q][r], wv[r], lg[e]);
      }
    }
    #pragma unroll
    for (int m = 1; m < 8; m <<= 1){
      S += __shfl_xor(S, m);
      Q += __shfl_xor(Q, m);
      #pragma unroll
      for (int e = 0; e < E; e++) lg[e] += __shfl_xor(lg[e], m);
    }

    float mu = S * (1.f / H);
    float var = Q * (1.f / H) - mu * mu;
    float rsig = rsqrtf(fmaxf(var, 0.f) + EPS);

    short8 s0, s1;
    #pragma unroll
    for (int r = 0; r < 4; ++r){
      s0[r]     = (short)f2bf((v[0][r] - mu) * rsig);
      s0[r + 4] = (short)f2bf((v[1][r] - mu) * rsig);
      s1[r]     = (short)f2bf((v[2][r] - mu) * rsig);
      s1[r + 4] = (short)f2bf((v[3][r] - mu) * rsig);
    }
    unsigned short* xo = xn + (size_t)tok * H + c8 * 16;
    *(short8*)xo = s0;
    *(short8*)(xo + 8) = s1;

    if (c8 == 0){
      float mx = -1e30f;
      #pragma unroll
      for (int e = 0; e < E; e++){ lg[e] += gbs[e]; mx = fmaxf(mx, lg[e]); }
      float p[E], sum = 0.f;
      #pragma unroll
      for (int e = 0; e < E; e++){ p[e] = __expf(lg[e] - mx); sum += p[e]; }
      float inv = 1.f / sum;
      int e0 = 0; float p0 = p[0];
      #pragma unroll
      for (int e = 1; e < E; e++) if (p[e] > p0){ e0 = e; p0 = p[e]; }
      int e1 = -1; float p1 = -1.f;
      #pragma unroll
      for (int e = 0; e < E; e++) if (e != e0 && p[e] > p1){ e1 = e; p1 = p[e]; }
      te[0][lt] = e0; tsc[0][lt] = p0 * inv; tlp[0][lt] = atomicAdd(&lcnt[e0], 1);
      te[1][lt] = e1; tsc[1][lt] = p1 * inv; tlp[1][lt] = atomicAdd(&lcnt[e1], 1);
    }
  }
  __syncthreads();
  if (tid < E) gbase[tid] = atomicAdd(&cnt[tid], lcnt[tid]);
  __syncthreads();
  if (tid < GATE_TPB){
    int tok = tok0 + tid;
    #pragma unroll
    for (int k2 = 0; k2 < 2; k2++){
      int ee = te[k2][tid];
      int pos = gbase[ee] + tlp[k2][tid];
      list[ee * N_TOK + pos] = tok;
      score[ee * N_TOK + pos] = tsc[k2][tid];
    }
  }
}

// ---------------- Kernel C: FUSED expert MLP, 1 wave = 16 slots -------------
// 64-thread blocks, 16KB LDS for the t tile (bf16, GEMM2 A-frag layout,
// same offset formulas as rounds 7/8's global-t). Removes the 100MB t
// round-trip and converts the latency-critical t re-read from L3 (~600cy)
// to LDS (~120cy). Stats stay in-register (every lane keeps its l15-token's
// rsig / mu*rsig after two xor-shuffles). Dense slot-space grid.
__global__ __launch_bounds__(64, 2) void k_mlp(
    const unsigned short* __restrict__ xn,
    const float* __restrict__ ln1g, const float* __restrict__ ln1b,
    const unsigned short* __restrict__ w1p,
    const float* __restrict__ ln2g, const float* __restrict__ ln2b,
    const unsigned short* __restrict__ w2p, const float* __restrict__ b2,
    const int* __restrict__ cnt, const int* __restrict__ list,
    const float* __restrict__ score, float* __restrict__ out){
  __shared__ __align__(16) unsigned short tls[16 * I_DIM];  // 16 KB

  int lane = threadIdx.x;
  int slot0 = blockIdx.x * 16;
  int base, ne;
  int e = slot_to_expert(cnt, slot0, base, ne);
  if (e < 0 || base >= ne) return;
  const int l15 = lane & 15, l4 = lane >> 4;

  int tok_ = base + l15 < ne ? list[e * N_TOK + base + l15] : 0;

  // ---- GEMM1 B-frags: a1 = gelu(xn*g1+b1); token=l15, h = kt*32+l4*8+j ----
  short8 b1f[4];
  const float* g1e = ln1g + e * H;
  const float* b1e = ln1b + e * H;
  #pragma unroll
  for (int kt = 0; kt < 4; ++kt){
    int h0 = kt * 32 + l4 * 8;
    float4 ga = *(const float4*)(g1e + h0), gbv = *(const float4*)(g1e + h0 + 4);
    float4 ba = *(const float4*)(b1e + h0), bbv = *(const float4*)(b1e + h0 + 4);
    short8 xv = *(const short8*)(xn + (size_t)tok_ * H + h0);
    short8 o;
    #pragma unroll
    for (int j = 0; j < 8; ++j){
      float f = bf2f((unsigned short)xv[j]);
      float gg = j < 4 ? ga[j] : gbv[j - 4];
      float bb_ = j < 4 ? ba[j] : bbv[j - 4];
      o[j] = (short)f2bf(gelu_fast(__builtin_fmaf(f, gg, bb_)));
    }
    b1f[kt] = o;
  }

  // ---- GEMM1^T in 4 chunks of 8 i-tiles; t (packed bf16) -> LDS -----------
  const unsigned short* w1e = w1p + ((size_t)e << 16);
  float S0 = 0.f, Q0 = 0.f;

  #pragma unroll
  for (int ch = 0; ch < 4; ++ch){
    f32x4 a0[8];
    #pragma unroll
    for (int ii = 0; ii < 8; ++ii){ f32x4 z = {0.f,0.f,0.f,0.f}; a0[ii] = z; }
    #pragma unroll
    for (int kt = 0; kt < 4; ++kt){
      #pragma unroll
      for (int ii = 0; ii < 8; ++ii){
        int it = ch * 8 + ii;
        short8 af = *(const short8*)(w1e + (size_t)(((it << 2) | kt) << 9) + lane * 8);
        a0[ii] = mfma16(af, b1f[kt], a0[ii]);
      }
    }
    #pragma unroll
    for (int ii = 0; ii < 8; ++ii){
      int it = ch * 8 + ii;
      int kt2 = it >> 1;
      int lh = (it * 2 + (l4 >> 1)) & 3;
      int off = ((kt2 * 4 + lh) * 16 + l15) * 8 + (l4 & 1) * 4;  // u16 units
      u32x2 w0;
      #pragma unroll
      for (int r = 0; r < 4; ++r){
        float v0 = a0[ii][r];
        S0 += v0; Q0 = __builtin_fmaf(v0, v0, Q0);
      }
      w0[0] = pack2(a0[ii][0], a0[ii][1]); w0[1] = pack2(a0[ii][2], a0[ii][3]);
      *(u32x2*)((char*)tls + (size_t)off * 2) = w0;
    }
  }

  // ---- LN2 stats: every lane ends with its l15-token's rsig / mu*rsig -----
  S0 += __shfl_xor(S0, 16); Q0 += __shfl_xor(Q0, 16);
  S0 += __shfl_xor(S0, 32); Q0 += __shfl_xor(Q0, 32);
  float mu = S0 * (1.f / I_DIM);
  float var = __builtin_fmaf(Q0, 1.f / I_DIM, -mu * mu);
  float rsig = rsqrtf(fmaxf(var, 0.f) + EPS);
  float mrs = mu * rsig;

  // ---- GEMM2: t from LDS (A-frag: token=l15, i=kt*32+l4*8+j) --------------
  const unsigned short* w2e = w2p + ((size_t)e << 16);
  const float* g2e = ln2g + e * I_DIM;
  const float* b2e = ln2b + e * I_DIM;

  f32x4 c0[8];
  #pragma unroll
  for (int ht = 0; ht < 8; ++ht){ f32x4 z = {0.f,0.f,0.f,0.f}; c0[ht] = z; }

  #pragma unroll
  for (int kt = 0; kt < 16; ++kt){
    int i0 = kt * 32 + l4 * 8;
    float4 g2a = *(const float4*)(g2e + i0), g2b = *(const float4*)(g2e + i0 + 4);
    float4 b2a = *(const float4*)(b2e + i0), b2b = *(const float4*)(b2e + i0 + 4);
    short8 tv0 = *(const short8*)((const char*)tls + (size_t)(kt * 64 + lane) * 16);
    short8 f0;
    #pragma unroll
    for (int j = 0; j < 8; ++j){
      float gg = j < 4 ? g2a[j] : g2b[j - 4];
      float bb_ = j < 4 ? b2a[j] : b2b[j - 4];
      float v0 = __builtin_fmaf(bf2f((unsigned short)tv0[j]), rsig, -mrs);
      f0[j] = (short)f2bf(gelu_fast(__builtin_fmaf(v0, gg, bb_)));
    }
    #pragma unroll
    for (int ht = 0; ht < 8; ++ht){
      short8 af = *(const short8*)(w2e + (size_t)(((ht << 4) | kt) << 9) + lane * 8);
      c0[ht] = mfma16(f0, af, c0[ht]);
    }
  }

  // ---- epilogue: token = base + l4*4 + r (row), h = ht*16 + l15 (col) -----
  int tokR[4]; float scR[4];
  #pragma unroll
  for (int r = 0; r < 4; ++r){
    int s = base + l4 * 4 + r;
    if (s < ne){ tokR[r] = list[e * N_TOK + s]; scR[r] = score[e * N_TOK + s]; }
    else       { tokR[r] = -1;                  scR[r] = 0.f; }
  }
  const float* b2r = b2 + e * H;
  float bb[8];
  #pragma unroll
  for (int ht = 0; ht < 8; ++ht) bb[ht] = b2r[ht * 16 + l15];

  #pragma unroll
  for (int r = 0; r < 4; ++r){
    if (tokR[r] >= 0){
      float* orow = out + (size_t)tokR[r] * H + l15;
      float sc = scR[r];
      #pragma unroll
      for (int ht = 0; ht < 8; ++ht)
        atomicAdd(orow + ht * 16, (c0[ht][r] + bb[ht]) * sc);
    }
  }
}

extern "C" void kernel_launch(void* const* d_in, const int* in_sizes, int n_in,
                              void* d_out, int out_size, void* d_ws, size_t ws_size,
                              hipStream_t stream){
  const float* x     = (const float*)d_in[0];
  const float* gw    = (const float*)d_in[1];
  const float* gb    = (const float*)d_in[2];
  const float* ln1g  = (const float*)d_in[3];
  const float* ln1b  = (const float*)d_in[4];
  const float* w1    = (const float*)d_in[5];
  const float* ln2g  = (const float*)d_in[6];
  const float* ln2b  = (const float*)d_in[7];
  const float* w2    = (const float*)d_in[8];
  const float* b2    = (const float*)d_in[9];
  float* out = (float*)d_out;

  char* w = (char*)d_ws;
  unsigned short* xn  = (unsigned short*)w;  w += (size_t)N_TOK * H * 2;      // 8.39 MB
  unsigned short* w1p = (unsigned short*)w;  w += (size_t)E * I_DIM * H * 2;  // 1.05 MB
  unsigned short* w2p = (unsigned short*)w;  w += (size_t)E * H * I_DIM * 2;  // 1.05 MB
  int*    list  = (int*)w;                   w += (size_t)E * N_TOK * 4;      // 1.05 MB
  float*  score = (float*)w;                 w += (size_t)E * N_TOK * 4;      // 1.05 MB
  int*    cnt   = (int*)w;                   w += 256;

  hipMemsetAsync(cnt, 0, 256, stream);
  hipMemsetAsync(out, 0, (size_t)out_size * sizeof(float), stream);

  k_prep<<<dim3(256), dim3(256), 0, stream>>>(w1, w2, w1p, w2p);
  k_gate<<<dim3(N_TOK / GATE_TPB), dim3(256), 0, stream>>>(x, gw, gb, xn, cnt, list, score);
  k_mlp<<<dim3(NSLOT_MAX / 16), dim3(64), 0, stream>>>(
      xn, ln1g, ln1b, w1p, ln2g, ln2b, w2p, b2, cnt, list, score, out);
}